// Round 3
// baseline (371.734 us; speedup 1.0000x reference)
//
#include <hip/hip_runtime.h>
#include <hip/hip_cooperative_groups.h>

namespace cg = cooperative_groups;

typedef float f32x4 __attribute__((ext_vector_type(4)));

// Geometry: L = 16384 tokens, Lc = 8192 chunks, H = 4096 hidden
// EMA recurrence y_i = A_i*y_{i-1} + Pc_i*concept_i, A scalar per chunk.
// Kernel 1 (setup): decode mask -> start[], A[], Pc[]
// Kernel 2 (cooperative, fused):
//   phase A: per-segment local scan -> Bend[g][H], Aseg[g]
//   phase B: per-channel carry chain across G segments (16 blocks)
//   phase C: rescan from exact carry, nontemporal write of token rows

#define SEG 64      // chunks per segment
#define TPB 256
#define SETUP_T 1024
#define MAXG 512

// ---------------- setup: decode mask, build start[], A[], Pc[] ----------------
__global__ void setup_kernel(const unsigned char* __restrict__ mask,
                             const float* __restrict__ probs,
                             float* __restrict__ A, float* __restrict__ Pc,
                             int* __restrict__ start, int L, int Lc) {
    __shared__ int flag;
    __shared__ int cnt[SETUP_T];
    const int t = threadIdx.x;
    if (t == 0) flag = 0;
    __syncthreads();

    // Detect encoding: int32 0/1 has all bytes at p%4!=0 zero.
    int local = 0;
    for (int p = t; p < L; p += SETUP_T) {
        if ((p & 3) && mask[p]) local = 1;
    }
    if (local) atomicOr(&flag, 1);
    __syncthreads();
    const bool isU8 = (flag != 0);
    const int* mask_i32 = (const int*)mask;

    const int per = (L + SETUP_T - 1) / SETUP_T;
    const int t0 = t * per;
    int c = 0;
    for (int k = 0; k < per; ++k) {
        int tok = t0 + k;
        if (tok < L) c += isU8 ? (mask[tok] != 0) : (mask_i32[tok] != 0);
    }
    cnt[t] = c;
    __syncthreads();
    for (int off = 1; off < SETUP_T; off <<= 1) {
        int v = 0;
        if (t >= off) v = cnt[t - off];
        __syncthreads();
        if (t >= off) cnt[t] += v;
        __syncthreads();
    }
    int rank = (t == 0) ? 0 : cnt[t - 1];
    for (int k = 0; k < per; ++k) {
        int tok = t0 + k;
        if (tok < L) {
            int m = isU8 ? (mask[tok] != 0) : (mask_i32[tok] != 0);
            if (m) {
                if (rank < Lc) {
                    start[rank] = tok;
                    float p = probs[tok];
                    A[rank]  = (rank == 0) ? 0.0f : (1.0f - p);
                    Pc[rank] = (rank == 0) ? 1.0f : p;
                }
                rank++;
            }
        }
    }
    if (t == 0) start[Lc] = L;
}

// ---------------- fused cooperative kernel ----------------
__global__ void __launch_bounds__(TPB)
fused_kernel(const float* __restrict__ cpt,
             const float* __restrict__ A, const float* __restrict__ Pc,
             const int* __restrict__ start,
             float* __restrict__ Bend, float* __restrict__ Aseg,
             float* __restrict__ carry, float* __restrict__ out,
             int H, int CG, int G) {
    cg::grid_group grid = cg::this_grid();

    const int g   = blockIdx.x / CG;
    const int cgi = blockIdx.x % CG;
    const int ch  = cgi * (TPB * 4) + threadIdx.x * 4;
    const int i0  = g * SEG;

    __shared__ float sA[SEG], sP[SEG];
    __shared__ int   sS[SEG + 1];
    for (int k = threadIdx.x; k < SEG; k += TPB)     { sA[k] = A[i0 + k]; sP[k] = Pc[i0 + k]; }
    for (int k = threadIdx.x; k < SEG + 1; k += TPB) { sS[k] = start[i0 + k]; }
    __syncthreads();

    const int strideF4 = H / 4;
    const float4* cp = (const float4*)(cpt + (size_t)i0 * H + ch);

    // ---- phase A: local segment scan -> Bend, Aseg ----
    {
        float4 y = make_float4(0.f, 0.f, 0.f, 0.f);
        float pa = 1.0f;
#pragma unroll 8
        for (int k = 0; k < SEG; ++k) {
            float a = sA[k], p = sP[k];
            float4 c = cp[(size_t)k * strideF4];
            y.x = a * y.x + p * c.x;
            y.y = a * y.y + p * c.y;
            y.z = a * y.z + p * c.z;
            y.w = a * y.w + p * c.w;
            pa *= a;
        }
        *(float4*)(Bend + (size_t)g * H + ch) = y;
        if (threadIdx.x == 0 && cgi == 0) Aseg[g] = pa;
    }
    __threadfence();
    grid.sync();

    // ---- phase B: per-channel carry chain (blocks 0 .. H/TPB-1) ----
    if ((int)blockIdx.x < H / TPB) {
        __shared__ float sAs[MAXG];
        for (int k = threadIdx.x; k < G; k += TPB) sAs[k] = Aseg[k];
        __syncthreads();
        const int c0 = blockIdx.x * TPB + threadIdx.x;
        float cr = 0.0f;
        carry[c0] = 0.0f;
#pragma unroll 4
        for (int gg = 1; gg < G; ++gg) {
            float b = Bend[(size_t)(gg - 1) * H + c0];
            cr = b + sAs[gg - 1] * cr;
            carry[(size_t)gg * H + c0] = cr;
        }
    }
    __threadfence();
    grid.sync();

    // ---- phase C: rescan from carry, fused token write (nontemporal) ----
    {
        float4 y = *(const float4*)(carry + (size_t)g * H + ch);
#pragma unroll 4
        for (int k = 0; k < SEG; ++k) {
            float a = sA[k], p = sP[k];
            float4 c = cp[(size_t)k * strideF4];
            y.x = a * y.x + p * c.x;
            y.y = a * y.y + p * c.y;
            y.z = a * y.z + p * c.z;
            y.w = a * y.w + p * c.w;
            f32x4 yv;
            yv.x = y.x; yv.y = y.y; yv.z = y.z; yv.w = y.w;
            const int te = sS[k + 1];
            for (int t = sS[k]; t < te; ++t) {
                __builtin_nontemporal_store(yv, (f32x4*)(out + (size_t)t * H + ch));
            }
        }
    }
}

extern "C" void kernel_launch(void* const* d_in, const int* in_sizes, int n_in,
                              void* d_out, int out_size, void* d_ws, size_t ws_size,
                              hipStream_t stream) {
    const float* cpt   = (const float*)d_in[0];                 // [1, Lc, H] f32
    const float* probs = (const float*)d_in[1];                 // [1, L, 1] f32
    const unsigned char* mask = (const unsigned char*)d_in[2];  // [1, L] bool/int

    const int L  = in_sizes[1];
    const int H  = out_size / L;          // 4096
    const int Lc = in_sizes[0] / H;       // 8192
    const int G  = Lc / SEG;              // 128
    const int CG = H / (TPB * 4);         // 4

    char* ws = (char*)d_ws;
    size_t off = 0;
    auto alloc = [&](size_t bytes) {
        size_t o = off;
        off += (bytes + 15) & ~(size_t)15;
        return (void*)(ws + o);
    };
    float* A     = (float*)alloc((size_t)Lc * 4);
    float* Pc    = (float*)alloc((size_t)Lc * 4);
    int*   start = (int*)  alloc((size_t)(Lc + 1) * 4);
    float* Aseg  = (float*)alloc((size_t)G * 4);
    float* Bend  = (float*)alloc((size_t)G * H * 4);
    float* carry = (float*)alloc((size_t)G * H * 4);
    (void)ws_size;

    hipLaunchKernelGGL(setup_kernel, dim3(1), dim3(SETUP_T), 0, stream,
                       mask, probs, A, Pc, start, L, Lc);

    float* outp = (float*)d_out;
    const float* cpt_a = cpt; const float* A_a = A; const float* Pc_a = Pc;
    const int* start_a = start;
    float* Bend_a = Bend; float* Aseg_a = Aseg; float* carry_a = carry;
    int H_a = H, CG_a = CG, G_a = G;
    void* args[] = {(void*)&cpt_a, (void*)&A_a, (void*)&Pc_a, (void*)&start_a,
                    (void*)&Bend_a, (void*)&Aseg_a, (void*)&carry_a, (void*)&outp,
                    (void*)&H_a, (void*)&CG_a, (void*)&G_a};
    (void)hipLaunchCooperativeKernel((void*)fused_kernel, dim3(G * CG), dim3(TPB),
                                     args, 0, stream);
}

// Round 4
// 132.501 us; speedup vs baseline: 2.8055x; 2.8055x over previous
//
#include <hip/hip_runtime.h>

typedef float f32x4 __attribute__((ext_vector_type(4)));

// Geometry: L = 16384 tokens, Lc = 8192 chunks, H = 4096 hidden
// EMA recurrence y_i = A_i*y_{i-1} + Pc_i*concept_i, A scalar per chunk.
//
// Pipeline (5 small kernels, all high-occupancy, no cooperative launch):
//   setup:      decode mask -> start[], A[], Pc[]
//   segsum:     per-segment (SEG=16) local scan -> Bend[G][H], Aseg[G]   (G=512, grid 2048)
//   carry1:     supersegment (16 segs) summaries -> Bend2[G2][H], Aseg2[G2] (G2=32)
//   carry2:     32-step chain -> carry2[G2][H] (exclusive carry at supersegment starts)
//   scan_write: per-segment block: inline-fix carry from <=15 Bend rows (L2-hot),
//               rescan segment, write token rows. (grid 2048)

#define SEG 16
#define TPB 256
#define SETUP_T 1024
#define SSEG 16        // segments per supersegment
#define MAXG2 64

// ---------------- setup ----------------
__global__ void __launch_bounds__(SETUP_T)
setup_kernel(const unsigned char* __restrict__ mask,
             const float* __restrict__ probs,
             float* __restrict__ A, float* __restrict__ Pc,
             int* __restrict__ start, int L, int Lc) {
    __shared__ int flag;
    __shared__ int wsum[SETUP_T / 64];
    const int t = threadIdx.x;
    const int lane = t & 63, wv = t >> 6;
    if (t == 0) flag = 0;
    __syncthreads();

    // fast path: 16 tokens per thread (L == 16384)
    int4 v8 = ((const int4*)mask)[t];   // 16 bytes, u8 view
    // encoding detect: int32 0/1 data has all bytes at pos%4!=0 zero
    int f = (v8.x & (int)0xFFFFFF00) | (v8.y & (int)0xFFFFFF00) |
            (v8.z & (int)0xFFFFFF00) | (v8.w & (int)0xFFFFFF00);
    if (f) atomicOr(&flag, 1);
    __syncthreads();
    const bool isU8 = (flag != 0);

    unsigned mbits = 0;
    if (isU8) {
        unsigned dw[4] = {(unsigned)v8.x, (unsigned)v8.y, (unsigned)v8.z, (unsigned)v8.w};
#pragma unroll
        for (int q = 0; q < 4; ++q)
#pragma unroll
            for (int b = 0; b < 4; ++b)
                if ((dw[q] >> (8 * b)) & 0xFFu) mbits |= 1u << (q * 4 + b);
    } else {
        const int4* m4 = (const int4*)mask;   // i32 view
#pragma unroll
        for (int q = 0; q < 4; ++q) {
            int4 w = m4[t * 4 + q];
            if (w.x) mbits |= 1u << (q * 4 + 0);
            if (w.y) mbits |= 1u << (q * 4 + 1);
            if (w.z) mbits |= 1u << (q * 4 + 2);
            if (w.w) mbits |= 1u << (q * 4 + 3);
        }
    }
    int c = __popc(mbits);

    // wave inclusive scan, then cross-wave offsets
    int s = c;
#pragma unroll
    for (int off = 1; off < 64; off <<= 1) {
        int v = __shfl_up(s, off, 64);
        if (lane >= off) s += v;
    }
    if (lane == 63) wsum[wv] = s;
    __syncthreads();
    if (t == 0) {
        int acc = 0;
        for (int w = 0; w < SETUP_T / 64; ++w) { int x = wsum[w]; wsum[w] = acc; acc += x; }
    }
    __syncthreads();

    int rank = wsum[wv] + (s - c);          // exclusive prefix
    const int t0 = t * 16;
#pragma unroll
    for (int k = 0; k < 16; ++k) {
        if ((mbits >> k) & 1u) {
            if (rank < Lc) {
                int tok = t0 + k;
                start[rank] = tok;
                float p = probs[tok];
                A[rank]  = (rank == 0) ? 0.0f : (1.0f - p);
                Pc[rank] = (rank == 0) ? 1.0f : p;
            }
            rank++;
        }
    }
    if (t == 0) start[Lc] = L;
}

// ---------------- pass A: per-segment summaries ----------------
__global__ void __launch_bounds__(TPB)
segsum_kernel(const float* __restrict__ cpt,
              const float* __restrict__ A, const float* __restrict__ Pc,
              float* __restrict__ Bend, float* __restrict__ Aseg,
              int H, int CG) {
    const int g  = blockIdx.x / CG;
    const int cg = blockIdx.x % CG;
    const int ch = cg * (TPB * 4) + threadIdx.x * 4;
    const int i0 = g * SEG;

    __shared__ float sA[SEG], sP[SEG];
    if (threadIdx.x < SEG) { sA[threadIdx.x] = A[i0 + threadIdx.x]; sP[threadIdx.x] = Pc[i0 + threadIdx.x]; }
    __syncthreads();

    const int strideF4 = H / 4;
    const float4* cp = (const float4*)(cpt + (size_t)i0 * H + ch);
    float4 y = make_float4(0.f, 0.f, 0.f, 0.f);
    float pa = 1.0f;
#pragma unroll 8
    for (int k = 0; k < SEG; ++k) {
        float a = sA[k], p = sP[k];
        float4 c = cp[(size_t)k * strideF4];
        y.x = a * y.x + p * c.x;
        y.y = a * y.y + p * c.y;
        y.z = a * y.z + p * c.z;
        y.w = a * y.w + p * c.w;
        pa *= a;
    }
    *(float4*)(Bend + (size_t)g * H + ch) = y;
    if (threadIdx.x == 0 && cg == 0) Aseg[g] = pa;
}

// ---------------- carry level 1: supersegment summaries ----------------
__global__ void __launch_bounds__(TPB)
carry1_kernel(const float* __restrict__ Bend, const float* __restrict__ Aseg,
              float* __restrict__ Bend2, float* __restrict__ Aseg2,
              int H, int CG) {
    const int g2 = blockIdx.x / CG;
    const int cg = blockIdx.x % CG;
    const int ch = cg * (TPB * 4) + threadIdx.x * 4;
    const int j0 = g2 * SSEG;

    float4 b = make_float4(0.f, 0.f, 0.f, 0.f);
    float pa = 1.0f;
#pragma unroll 8
    for (int j = 0; j < SSEG; ++j) {
        float a = Aseg[j0 + j];
        float4 bj = *(const float4*)(Bend + (size_t)(j0 + j) * H + ch);
        b.x = bj.x + a * b.x;
        b.y = bj.y + a * b.y;
        b.z = bj.z + a * b.z;
        b.w = bj.w + a * b.w;
        pa *= a;
    }
    *(float4*)(Bend2 + (size_t)g2 * H + ch) = b;
    if (threadIdx.x == 0 && cg == 0) Aseg2[g2] = pa;
}

// ---------------- carry level 2: chain over supersegments ----------------
__global__ void __launch_bounds__(TPB)
carry2_kernel(const float* __restrict__ Bend2, const float* __restrict__ Aseg2,
              float* __restrict__ carry2, int H, int G2) {
    __shared__ float sA2[MAXG2];
    const int c0 = blockIdx.x * TPB + threadIdx.x;
    if (threadIdx.x < G2) sA2[threadIdx.x] = Aseg2[threadIdx.x];
    __syncthreads();
    float cr = 0.0f;
    carry2[c0] = 0.0f;
#pragma unroll 4
    for (int g2 = 1; g2 < G2; ++g2) {
        float b = Bend2[(size_t)(g2 - 1) * H + c0];
        cr = b + sA2[g2 - 1] * cr;
        carry2[(size_t)g2 * H + c0] = cr;
    }
}

// ---------------- pass C: inline carry fix + rescan + token writes ----------------
__global__ void __launch_bounds__(TPB)
scan_write_kernel(const float* __restrict__ cpt,
                  const float* __restrict__ A, const float* __restrict__ Pc,
                  const int* __restrict__ start,
                  const float* __restrict__ Bend, const float* __restrict__ Aseg,
                  const float* __restrict__ carry2,
                  float* __restrict__ out, int H, int CG) {
    const int g  = blockIdx.x / CG;
    const int cg = blockIdx.x % CG;
    const int ch = cg * (TPB * 4) + threadIdx.x * 4;
    const int i0 = g * SEG;

    __shared__ float sA[SEG], sP[SEG];
    __shared__ int   sS[SEG + 1];
    if (threadIdx.x < SEG)     { sA[threadIdx.x] = A[i0 + threadIdx.x]; sP[threadIdx.x] = Pc[i0 + threadIdx.x]; }
    if (threadIdx.x < SEG + 1) { sS[threadIdx.x] = start[i0 + threadIdx.x]; }
    __syncthreads();

    // exclusive carry at this segment: carry2 at supersegment start, then <=15 Bend rows
    const int g2 = g / SSEG;
    float4 y = *(const float4*)(carry2 + (size_t)g2 * H + ch);
    for (int j = g2 * SSEG; j < g; ++j) {
        float a = Aseg[j];
        float4 b = *(const float4*)(Bend + (size_t)j * H + ch);
        y.x = b.x + a * y.x;
        y.y = b.y + a * y.y;
        y.z = b.z + a * y.z;
        y.w = b.w + a * y.w;
    }

    const int strideF4 = H / 4;
    const float4* cp = (const float4*)(cpt + (size_t)i0 * H + ch);
#pragma unroll 4
    for (int k = 0; k < SEG; ++k) {
        float a = sA[k], p = sP[k];
        float4 c = cp[(size_t)k * strideF4];
        y.x = a * y.x + p * c.x;
        y.y = a * y.y + p * c.y;
        y.z = a * y.z + p * c.z;
        y.w = a * y.w + p * c.w;
        const int te = sS[k + 1];
        for (int t = sS[k]; t < te; ++t) {
            *(float4*)(out + (size_t)t * H + ch) = y;
        }
    }
}

extern "C" void kernel_launch(void* const* d_in, const int* in_sizes, int n_in,
                              void* d_out, int out_size, void* d_ws, size_t ws_size,
                              hipStream_t stream) {
    const float* cpt   = (const float*)d_in[0];                 // [1, Lc, H] f32
    const float* probs = (const float*)d_in[1];                 // [1, L, 1] f32
    const unsigned char* mask = (const unsigned char*)d_in[2];  // [1, L] bool/int

    const int L  = in_sizes[1];           // 16384
    const int H  = out_size / L;          // 4096
    const int Lc = in_sizes[0] / H;       // 8192
    const int G  = Lc / SEG;              // 512
    const int G2 = G / SSEG;              // 32
    const int CG = H / (TPB * 4);         // 4

    char* ws = (char*)d_ws;
    size_t off = 0;
    auto alloc = [&](size_t bytes) {
        size_t o = off;
        off += (bytes + 255) & ~(size_t)255;
        return (void*)(ws + o);
    };
    float* A      = (float*)alloc((size_t)Lc * 4);
    float* Pc     = (float*)alloc((size_t)Lc * 4);
    int*   start  = (int*)  alloc((size_t)(Lc + 1) * 4);
    float* Aseg   = (float*)alloc((size_t)G * 4);
    float* Aseg2  = (float*)alloc((size_t)G2 * 4);
    float* Bend   = (float*)alloc((size_t)G * H * 4);    // 8 MB
    float* Bend2  = (float*)alloc((size_t)G2 * H * 4);   // 0.5 MB
    float* carry2 = (float*)alloc((size_t)G2 * H * 4);   // 0.5 MB
    (void)ws_size;

    hipLaunchKernelGGL(setup_kernel, dim3(1), dim3(SETUP_T), 0, stream,
                       mask, probs, A, Pc, start, L, Lc);
    hipLaunchKernelGGL(segsum_kernel, dim3(G * CG), dim3(TPB), 0, stream,
                       cpt, A, Pc, Bend, Aseg, H, CG);
    hipLaunchKernelGGL(carry1_kernel, dim3(G2 * CG), dim3(TPB), 0, stream,
                       Bend, Aseg, Bend2, Aseg2, H, CG);
    hipLaunchKernelGGL(carry2_kernel, dim3(H / TPB), dim3(TPB), 0, stream,
                       Bend2, Aseg2, carry2, H, G2);
    hipLaunchKernelGGL(scan_write_kernel, dim3(G * CG), dim3(TPB), 0, stream,
                       cpt, A, Pc, start, Bend, Aseg, carry2,
                       (float*)d_out, H, CG);
}